// Round 3
// baseline (1004.307 us; speedup 1.0000x reference)
//
#include <hip/hip_runtime.h>
#include <stdint.h>

// TreeLSTM cell fused kernel, round 3: barrier-free streaming design.
// 16 nb-groups (16 gate-cols each of i,o,u,f). Per block: W-tile (64x256 bf16)
// resident in LDS; waves grid-stride over 16-row x-tiles with zero barriers.
// Swapped-operand MFMA -> lane-local epilogue, float4 I/O everywhere.

typedef __attribute__((ext_vector_type(8))) short bf16x8;
typedef __attribute__((ext_vector_type(4))) float f32x4;

#define N_ROWS 200000
#define NT 512
#define J_PER_NB 32
#define SLOTS 256        // J_PER_NB * 8 wave-slots per nb group
#define TILES 12500      // N_ROWS / 16
#define WSTR 264         // LDS row stride in shorts (256 + 8 pad)

__device__ __forceinline__ short f2bf(float f) {
    union { float f; uint32_t u; } v; v.f = f;
    return (short)((v.u + 0x7fffu + ((v.u >> 16) & 1u)) >> 16);
}
__device__ __forceinline__ float fsig(float x) { return 1.0f / (1.0f + __expf(-x)); }
__device__ __forceinline__ float ftanh(float x) {
    float e = __expf(2.0f * x);
    return 1.0f - 2.0f / (e + 1.0f);
}
__device__ __forceinline__ bf16x8 pack8(float4 a, float4 b) {
    bf16x8 o;
    o[0] = f2bf(a.x); o[1] = f2bf(a.y); o[2] = f2bf(a.z); o[3] = f2bf(a.w);
    o[4] = f2bf(b.x); o[5] = f2bf(b.y); o[6] = f2bf(b.z); o[7] = f2bf(b.w);
    return o;
}

__global__ __launch_bounds__(NT, 4)
void treelstm_fused(const float* __restrict__ x,
                    const float* __restrict__ Uh,
                    const float* __restrict__ fc,
                    const float* __restrict__ W_iou,
                    const float* __restrict__ b_iou,
                    const float* __restrict__ W_f,
                    const float* __restrict__ b_f,
                    float* __restrict__ out) {
    __shared__ short wlds[64 * WSTR];          // 33792 B

    const int tid  = threadIdx.x;
    const int lane = tid & 63;
    const int w    = tid >> 6;
    const int bcol = lane & 15;                // x-row within tile / W-col within m-block
    const int q    = lane >> 4;                // k-chunk group

    const int bid = blockIdx.x;
    const int nb  = bid >> 5;                  // 0..15: gate-col slice (16 cols/gate)
    const int j   = bid & 31;                  // sibling idx; XCD = j%8 for all nb

    // ---- prologue: stage W tile once. LDS row c: gate g=c>>4, col nb*16+(c&15) ----
    {
        const int c  = tid >> 3;               // 0..63
        const int kc = tid & 7;                // 32-float K chunk
        const int g  = c >> 4;                 // 0:i 1:o 2:u 3:f
        const int kg = nb * 16 + (c & 15);
        const float* wr = (g < 3) ? (W_iou + (size_t)(g * 256 + kg) * 256)
                                  : (W_f + (size_t)kg * 256);
        const float4* p = (const float4*)(wr + kc * 32);
        short* dst = &wlds[c * WSTR + kc * 32];
#pragma unroll
        for (int i2 = 0; i2 < 4; ++i2)
            *(bf16x8*)&dst[i2 * 8] = pack8(p[2 * i2], p[2 * i2 + 1]);
    }
    __syncthreads();                           // the ONLY barrier

    // biases: loop-invariant, lane-local k-quad kb..kb+3
    const int kb = nb * 16 + q * 4;
    const float4 bi  = *(const float4*)&b_iou[kb];
    const float4 bo  = *(const float4*)&b_iou[256 + kb];
    const float4 bu  = *(const float4*)&b_iou[512 + kb];
    const float4 bfv = *(const float4*)&b_f[kb];

    float* out_h = out;
    float* out_c = out + (size_t)N_ROWS * 256;
    float* out_f = out + 2 * (size_t)N_ROWS * 256;

    const int slot = j * 8 + w;                // 0..255 within nb group
    for (int t = slot; t < TILES; t += SLOTS) {
        const int n = t * 16 + bcol;           // this lane's x row (exact, no guard)
        const float* xr = x + (size_t)n * 256 + q * 8;

        // x fragments: global -> reg -> bf16, 8 loads in flight per half
        bf16x8 xf[8];
#pragma unroll
        for (int h2 = 0; h2 < 2; ++h2) {
            float4 xa[8];
#pragma unroll
            for (int ks = 0; ks < 4; ++ks) {
                xa[2 * ks]     = *(const float4*)(xr + (h2 * 4 + ks) * 32);
                xa[2 * ks + 1] = *(const float4*)(xr + (h2 * 4 + ks) * 32 + 4);
            }
#pragma unroll
            for (int ks = 0; ks < 4; ++ks)
                xf[h2 * 4 + ks] = pack8(xa[2 * ks], xa[2 * ks + 1]);
        }

        f32x4 acc[4];
#pragma unroll
        for (int m = 0; m < 4; ++m) acc[m] = (f32x4){0.f, 0.f, 0.f, 0.f};

#pragma unroll
        for (int ks = 0; ks < 8; ++ks) {
#pragma unroll
            for (int m = 0; m < 4; ++m) {
                bf16x8 wf = *(const bf16x8*)&wlds[(m * 16 + bcol) * WSTR + ks * 32 + q * 8];
                // swapped operands: D[row=q*4+r -> W-col m*16+q*4+r][col=lane&15 -> x-row]
                acc[m] = __builtin_amdgcn_mfma_f32_16x16x32_bf16(wf, xf[ks], acc[m], 0, 0, 0);
            }
        }

        // ---- lane-local epilogue: acc[0]=i, acc[1]=o, acc[2]=u, acc[3]=f at k=kb+r ----
        const float* uh = Uh + (size_t)n * 768 + kb;
        const float4 ui = *(const float4*)(uh);
        const float4 uo = *(const float4*)(uh + 256);
        const float4 uu = *(const float4*)(uh + 512);
        const float4 fv = *(const float4*)(fc + (size_t)n * 256 + kb);

        float4 cc, hh, ff;
        cc.x = fsig(acc[0][0] + bi.x + ui.x) * ftanh(acc[2][0] + bu.x + uu.x) + fv.x;
        cc.y = fsig(acc[0][1] + bi.y + ui.y) * ftanh(acc[2][1] + bu.y + uu.y) + fv.y;
        cc.z = fsig(acc[0][2] + bi.z + ui.z) * ftanh(acc[2][2] + bu.z + uu.z) + fv.z;
        cc.w = fsig(acc[0][3] + bi.w + ui.w) * ftanh(acc[2][3] + bu.w + uu.w) + fv.w;
        hh.x = fsig(acc[1][0] + bo.x + uo.x) * ftanh(cc.x);
        hh.y = fsig(acc[1][1] + bo.y + uo.y) * ftanh(cc.y);
        hh.z = fsig(acc[1][2] + bo.z + uo.z) * ftanh(cc.z);
        hh.w = fsig(acc[1][3] + bo.w + uo.w) * ftanh(cc.w);
        ff.x = acc[3][0] + bfv.x;
        ff.y = acc[3][1] + bfv.y;
        ff.z = acc[3][2] + bfv.z;
        ff.w = acc[3][3] + bfv.w;

        const size_t oidx = (size_t)n * 256 + kb;
        *(float4*)(out_h + oidx) = hh;
        *(float4*)(out_c + oidx) = cc;
        *(float4*)(out_f + oidx) = ff;
    }
}

extern "C" void kernel_launch(void* const* d_in, const int* in_sizes, int n_in,
                              void* d_out, int out_size, void* d_ws, size_t ws_size,
                              hipStream_t stream) {
    const float* x     = (const float*)d_in[0];
    const float* Uh    = (const float*)d_in[1];
    const float* fc    = (const float*)d_in[2];
    const float* W_iou = (const float*)d_in[3];
    const float* b_iou = (const float*)d_in[4];
    const float* W_f   = (const float*)d_in[5];
    const float* b_f   = (const float*)d_in[6];
    float* out = (float*)d_out;

    dim3 grid(16 * J_PER_NB);     // 512 blocks = 2/CU, siblings share XCD (j%8)
    dim3 block(NT);
    treelstm_fused<<<grid, block, 0, stream>>>(x, Uh, fc, W_iou, b_iou, W_f, b_f, out);
}

// Round 4
// 934.836 us; speedup vs baseline: 1.0743x; 1.0743x over previous
//
#include <hip/hip_runtime.h>
#include <stdint.h>

// TreeLSTM fused, round 4: full-width barrier-free streaming.
// Block = 32 x-rows x all 1024 cols (16 kl-slices x 4 gates), 8 waves.
// W pre-packed to bf16 MFMA-fragment order in d_ws (L2-resident); x read
// from HBM exactly once; zero LDS, zero barriers in the main loop.

typedef __attribute__((ext_vector_type(8))) short bf16x8;
typedef __attribute__((ext_vector_type(4))) float f32x4;

#define N_ROWS 200000
#define NPASS 6250      // N_ROWS / 32
#define NBLK 256

__device__ __forceinline__ short f2bf(float f) {
    union { float f; uint32_t u; } v; v.f = f;
    return (short)((v.u + 0x7fffu + ((v.u >> 16) & 1u)) >> 16);
}
__device__ __forceinline__ float fsig(float x) { return 1.0f / (1.0f + __expf(-x)); }
__device__ __forceinline__ float ftanh(float x) {
    float e = __expf(2.0f * x);
    return 1.0f - 2.0f / (e + 1.0f);
}
__device__ __forceinline__ bf16x8 pack8(float4 a, float4 b) {
    bf16x8 o;
    o[0] = f2bf(a.x); o[1] = f2bf(a.y); o[2] = f2bf(a.z); o[3] = f2bf(a.w);
    o[4] = f2bf(b.x); o[5] = f2bf(b.y); o[6] = f2bf(b.z); o[7] = f2bf(b.w);
    return o;
}

// Pack W (f32) -> bf16 fragments: unit U=(s*4+g)*8+ks holds 64 lanes x 16B.
// Lane l of unit U = A-frag for tile (slice s, gate g), K-step ks:
//   A[row = l&15 -> col C=g*256+s*16+row][k = ks*32+(l>>4)*8 + 0..7]
__global__ void pack_w(const float* __restrict__ W_iou,
                       const float* __restrict__ W_f,
                       short* __restrict__ wpk) {
    const int task = blockIdx.x * 256 + threadIdx.x;   // 0..32767
    const int l = task & 63, U = task >> 6;
    const int ks = U & 7, g = (U >> 3) & 3, s = U >> 5;
    const int r = l & 15, q = l >> 4;
    const int C = s * 16 + r;
    const float* wr = (g < 3) ? (W_iou + (size_t)(g * 256 + C) * 256)
                              : (W_f + (size_t)C * 256);
    const float4* p = (const float4*)(wr + ks * 32 + q * 8);
    *(bf16x8*)(wpk + (size_t)task * 8) = pack8(p[0], p[1]);
}

template<bool PK>
__global__ __launch_bounds__(512, 2)
void treelstm_main(const float* __restrict__ x,
                   const float* __restrict__ Uh,
                   const float* __restrict__ fc,
                   const float* __restrict__ W_iou,
                   const float* __restrict__ b_iou,
                   const float* __restrict__ W_f,
                   const float* __restrict__ b_f,
                   const short* __restrict__ wpk,
                   float* __restrict__ out) {
    const int tid  = threadIdx.x;
    const int lane = tid & 63;
    const int w    = tid >> 6;          // wave 0..7 -> slices 2w, 2w+1
    const int q    = lane >> 4;
    const int bcol = lane & 15;
    const bf16x8* wp = (const bf16x8*)wpk;

    float* out_h = out;
    float* out_c = out + (size_t)N_ROWS * 256;
    float* out_f = out + 2 * (size_t)N_ROWS * 256;

    for (int t = blockIdx.x; t < NPASS; t += NBLK) {
        const int n0 = t * 32;
        f32x4 acc[2][2][4];                         // [rowgroup][z][gate]
#pragma unroll
        for (int a = 0; a < 2; ++a)
#pragma unroll
            for (int b = 0; b < 2; ++b)
#pragma unroll
                for (int g = 0; g < 4; ++g) acc[a][b][g] = (f32x4){0.f, 0.f, 0.f, 0.f};

#pragma unroll
        for (int kh = 0; kh < 2; ++kh) {
            // ---- x fragments: 16 coalesced dwordx4 in flight, then pack ----
            bf16x8 xf[2][4];
            {
                float4 xa[16];
#pragma unroll
                for (int r2 = 0; r2 < 2; ++r2)
#pragma unroll
                    for (int ks = 0; ks < 4; ++ks) {
                        const float* xr = x + (size_t)(n0 + r2 * 16 + bcol) * 256
                                        + kh * 128 + ks * 32 + q * 8;
                        xa[(r2 * 4 + ks) * 2]     = *(const float4*)xr;
                        xa[(r2 * 4 + ks) * 2 + 1] = *(const float4*)(xr + 4);
                    }
#pragma unroll
                for (int r2 = 0; r2 < 2; ++r2)
#pragma unroll
                    for (int ks = 0; ks < 4; ++ks)
                        xf[r2][ks] = pack8(xa[(r2 * 4 + ks) * 2], xa[(r2 * 4 + ks) * 2 + 1]);
            }
            // ---- W fragments from packed L2 stream + MFMA ----
#pragma unroll
            for (int ks = 0; ks < 4; ++ks) {
                const int ksg = kh * 4 + ks;
                bf16x8 wf[2][4];
#pragma unroll
                for (int z = 0; z < 2; ++z)
#pragma unroll
                    for (int g = 0; g < 4; ++g) {
                        if constexpr (PK) {
                            wf[z][g] = wp[(size_t)((((2 * w + z) * 4 + g) * 8) + ksg) * 64 + lane];
                        } else {
                            const int C = (2 * w + z) * 16 + bcol;
                            const float* wr = (g < 3) ? (W_iou + (size_t)(g * 256 + C) * 256)
                                                      : (W_f + (size_t)C * 256);
                            const float4* pw = (const float4*)(wr + ksg * 32 + q * 8);
                            wf[z][g] = pack8(pw[0], pw[1]);
                        }
                    }
#pragma unroll
                for (int z = 0; z < 2; ++z)
#pragma unroll
                    for (int g = 0; g < 4; ++g)
#pragma unroll
                        for (int r2 = 0; r2 < 2; ++r2)
                            acc[r2][z][g] = __builtin_amdgcn_mfma_f32_16x16x32_bf16(
                                wf[z][g], xf[r2][ks], acc[r2][z][g], 0, 0, 0);
            }
        }

        // ---- lane-local epilogue: gate g at kl = s*16 + q*4 + r ----
#pragma unroll
        for (int r2 = 0; r2 < 2; ++r2) {
            const int n = n0 + r2 * 16 + bcol;
#pragma unroll
            for (int z = 0; z < 2; ++z) {
                const int kb = (2 * w + z) * 16 + q * 4;
                const float4 bi  = *(const float4*)&b_iou[kb];
                const float4 bo  = *(const float4*)&b_iou[256 + kb];
                const float4 bu  = *(const float4*)&b_iou[512 + kb];
                const float4 bf4 = *(const float4*)&b_f[kb];
                const float* uh = Uh + (size_t)n * 768 + kb;
                const float4 ui = *(const float4*)uh;
                const float4 uo = *(const float4*)(uh + 256);
                const float4 uu = *(const float4*)(uh + 512);
                const float4 fv = *(const float4*)(fc + (size_t)n * 256 + kb);
                const f32x4 ai = acc[r2][z][0], ao = acc[r2][z][1];
                const f32x4 au = acc[r2][z][2], af = acc[r2][z][3];
                float4 cc, hh, ff;
                cc.x = fsig(ai[0] + bi.x + ui.x) * ftanh(au[0] + bu.x + uu.x) + fv.x;
                cc.y = fsig(ai[1] + bi.y + ui.y) * ftanh(au[1] + bu.y + uu.y) + fv.y;
                cc.z = fsig(ai[2] + bi.z + ui.z) * ftanh(au[2] + bu.z + uu.z) + fv.z;
                cc.w = fsig(ai[3] + bi.w + ui.w) * ftanh(au[3] + bu.w + uu.w) + fv.w;
                hh.x = fsig(ao[0] + bo.x + uo.x) * ftanh(cc.x);
                hh.y = fsig(ao[1] + bo.y + uo.y) * ftanh(cc.y);
                hh.z = fsig(ao[2] + bo.z + uo.z) * ftanh(cc.z);
                hh.w = fsig(ao[3] + bo.w + uo.w) * ftanh(cc.w);
                ff.x = af[0] + bf4.x;
                ff.y = af[1] + bf4.y;
                ff.z = af[2] + bf4.z;
                ff.w = af[3] + bf4.w;
                const size_t oidx = (size_t)n * 256 + kb;
                *(float4*)(out_h + oidx) = hh;
                *(float4*)(out_c + oidx) = cc;
                *(float4*)(out_f + oidx) = ff;
            }
        }
    }
}

extern "C" void kernel_launch(void* const* d_in, const int* in_sizes, int n_in,
                              void* d_out, int out_size, void* d_ws, size_t ws_size,
                              hipStream_t stream) {
    const float* x     = (const float*)d_in[0];
    const float* Uh    = (const float*)d_in[1];
    const float* fc    = (const float*)d_in[2];
    const float* W_iou = (const float*)d_in[3];
    const float* b_iou = (const float*)d_in[4];
    const float* W_f   = (const float*)d_in[5];
    const float* b_f   = (const float*)d_in[6];
    float* out = (float*)d_out;
    short* wpk = (short*)d_ws;

    if (ws_size >= 512 * 1024) {
        pack_w<<<128, 256, 0, stream>>>(W_iou, W_f, wpk);
        treelstm_main<true><<<NBLK, 512, 0, stream>>>(x, Uh, fc, W_iou, b_iou,
                                                      W_f, b_f, wpk, out);
    } else {
        treelstm_main<false><<<NBLK, 512, 0, stream>>>(x, Uh, fc, W_iou, b_iou,
                                                       W_f, b_f, wpk, out);
    }
}

// Round 5
// 608.598 us; speedup vs baseline: 1.6502x; 1.5360x over previous
//
#include <hip/hip_runtime.h>
#include <stdint.h>

// TreeLSTM fused, round 5: R4 structure with the two measured bugs fixed.
// (1) grid = 6250 one-shot blocks (was 256 persistent -> 1 block/CU cap);
// (2) non-temporal Uh/fc loads + out stores so the 512KB packed-W stream
//     stays L2-resident (was thrashed -> 0.8GB excess HBM fetch).
// Block = 32 x-rows x all 1024 cols, 8 waves, zero LDS, zero barriers.

typedef __attribute__((ext_vector_type(8))) short bf16x8;
typedef __attribute__((ext_vector_type(4))) float f32x4;
typedef __attribute__((ext_vector_type(4))) float f4v;

#define N_ROWS 200000
#define TILES 6250      // N_ROWS / 32

__device__ __forceinline__ short f2bf(float f) {
    union { float f; uint32_t u; } v; v.f = f;
    return (short)((v.u + 0x7fffu + ((v.u >> 16) & 1u)) >> 16);
}
__device__ __forceinline__ float fsig(float x) { return 1.0f / (1.0f + __expf(-x)); }
__device__ __forceinline__ float ftanh(float x) {
    float e = __expf(2.0f * x);
    return 1.0f - 2.0f / (e + 1.0f);
}
__device__ __forceinline__ bf16x8 pack8(f4v a, f4v b) {
    bf16x8 o;
    o[0] = f2bf(a.x); o[1] = f2bf(a.y); o[2] = f2bf(a.z); o[3] = f2bf(a.w);
    o[4] = f2bf(b.x); o[5] = f2bf(b.y); o[6] = f2bf(b.z); o[7] = f2bf(b.w);
    return o;
}

// Pack W (f32) -> bf16 fragments: unit U=(s*4+g)*8+ks holds 64 lanes x 16B.
// Lane l of unit U = A-frag for tile (slice s, gate g), K-step ks:
//   A[row = l&15 -> col C=s*16+row of gate g][k = ks*32+(l>>4)*8 + 0..7]
__global__ void pack_w(const float* __restrict__ W_iou,
                       const float* __restrict__ W_f,
                       short* __restrict__ wpk) {
    const int task = blockIdx.x * 256 + threadIdx.x;   // 0..32767
    const int l = task & 63, U = task >> 6;
    const int ks = U & 7, g = (U >> 3) & 3, s = U >> 5;
    const int r = l & 15, q = l >> 4;
    const int C = s * 16 + r;
    const float* wr = (g < 3) ? (W_iou + (size_t)(g * 256 + C) * 256)
                              : (W_f + (size_t)C * 256);
    const f4v* p = (const f4v*)(wr + ks * 32 + q * 8);
    *(bf16x8*)(wpk + (size_t)task * 8) = pack8(p[0], p[1]);
}

template<bool PK>
__global__ __launch_bounds__(512, 2)
void treelstm_main(const float* __restrict__ x,
                   const float* __restrict__ Uh,
                   const float* __restrict__ fc,
                   const float* __restrict__ W_iou,
                   const float* __restrict__ b_iou,
                   const float* __restrict__ W_f,
                   const float* __restrict__ b_f,
                   const short* __restrict__ wpk,
                   float* __restrict__ out) {
    const int tid  = threadIdx.x;
    const int lane = tid & 63;
    const int w    = tid >> 6;          // wave 0..7 -> slices 2w, 2w+1
    const int q    = lane >> 4;
    const int bcol = lane & 15;
    const bf16x8* wp = (const bf16x8*)wpk;

    float* out_h = out;
    float* out_c = out + (size_t)N_ROWS * 256;
    float* out_f = out + 2 * (size_t)N_ROWS * 256;

    const int n0 = blockIdx.x * 32;
    f32x4 acc[2][2][4];                         // [rowgroup][z][gate]
#pragma unroll
    for (int a = 0; a < 2; ++a)
#pragma unroll
        for (int b = 0; b < 2; ++b)
#pragma unroll
            for (int g = 0; g < 4; ++g) acc[a][b][g] = (f32x4){0.f, 0.f, 0.f, 0.f};

#pragma unroll
    for (int kh = 0; kh < 2; ++kh) {
        // ---- x fragments: 16 coalesced dwordx4 in flight, then pack ----
        bf16x8 xf[2][4];
        {
            f4v xa[16];
#pragma unroll
            for (int r2 = 0; r2 < 2; ++r2)
#pragma unroll
                for (int ks = 0; ks < 4; ++ks) {
                    const float* xr = x + (size_t)(n0 + r2 * 16 + bcol) * 256
                                    + kh * 128 + ks * 32 + q * 8;
                    xa[(r2 * 4 + ks) * 2]     = *(const f4v*)xr;
                    xa[(r2 * 4 + ks) * 2 + 1] = *(const f4v*)(xr + 4);
                }
#pragma unroll
            for (int r2 = 0; r2 < 2; ++r2)
#pragma unroll
                for (int ks = 0; ks < 4; ++ks)
                    xf[r2][ks] = pack8(xa[(r2 * 4 + ks) * 2], xa[(r2 * 4 + ks) * 2 + 1]);
        }
        // ---- W fragments from packed L2-resident stream + MFMA ----
#pragma unroll
        for (int ks = 0; ks < 4; ++ks) {
            const int ksg = kh * 4 + ks;
            bf16x8 wf[2][4];
#pragma unroll
            for (int z = 0; z < 2; ++z)
#pragma unroll
                for (int g = 0; g < 4; ++g) {
                    if constexpr (PK) {
                        wf[z][g] = wp[(size_t)((((2 * w + z) * 4 + g) * 8) + ksg) * 64 + lane];
                    } else {
                        const int C = (2 * w + z) * 16 + bcol;
                        const float* wr = (g < 3) ? (W_iou + (size_t)(g * 256 + C) * 256)
                                                  : (W_f + (size_t)C * 256);
                        const f4v* pw = (const f4v*)(wr + ksg * 32 + q * 8);
                        wf[z][g] = pack8(pw[0], pw[1]);
                    }
                }
#pragma unroll
            for (int z = 0; z < 2; ++z)
#pragma unroll
                for (int g = 0; g < 4; ++g)
#pragma unroll
                    for (int r2 = 0; r2 < 2; ++r2)
                        acc[r2][z][g] = __builtin_amdgcn_mfma_f32_16x16x32_bf16(
                            wf[z][g], xf[r2][ks], acc[r2][z][g], 0, 0, 0);
        }
    }

    // ---- lane-local epilogue: gate g at kl = s*16 + q*4 + r; nt streaming ----
#pragma unroll
    for (int r2 = 0; r2 < 2; ++r2) {
        const int n = n0 + r2 * 16 + bcol;
#pragma unroll
        for (int z = 0; z < 2; ++z) {
            const int kb = (2 * w + z) * 16 + q * 4;
            const f4v bi  = *(const f4v*)&b_iou[kb];
            const f4v bo  = *(const f4v*)&b_iou[256 + kb];
            const f4v bu  = *(const f4v*)&b_iou[512 + kb];
            const f4v bf4 = *(const f4v*)&b_f[kb];
            const float* uh = Uh + (size_t)n * 768 + kb;
            const f4v ui = __builtin_nontemporal_load((const f4v*)uh);
            const f4v uo = __builtin_nontemporal_load((const f4v*)(uh + 256));
            const f4v uu = __builtin_nontemporal_load((const f4v*)(uh + 512));
            const f4v fv = __builtin_nontemporal_load((const f4v*)(fc + (size_t)n * 256 + kb));
            const f32x4 ai = acc[r2][z][0], ao = acc[r2][z][1];
            const f32x4 au = acc[r2][z][2], af = acc[r2][z][3];
            f4v cc, hh, ff;
            cc.x = fsig(ai[0] + bi.x + ui.x) * ftanh(au[0] + bu.x + uu.x) + fv.x;
            cc.y = fsig(ai[1] + bi.y + ui.y) * ftanh(au[1] + bu.y + uu.y) + fv.y;
            cc.z = fsig(ai[2] + bi.z + ui.z) * ftanh(au[2] + bu.z + uu.z) + fv.z;
            cc.w = fsig(ai[3] + bi.w + ui.w) * ftanh(au[3] + bu.w + uu.w) + fv.w;
            hh.x = fsig(ao[0] + bo.x + uo.x) * ftanh(cc.x);
            hh.y = fsig(ao[1] + bo.y + uo.y) * ftanh(cc.y);
            hh.z = fsig(ao[2] + bo.z + uo.z) * ftanh(cc.z);
            hh.w = fsig(ao[3] + bo.w + uo.w) * ftanh(cc.w);
            ff.x = af[0] + bf4.x;
            ff.y = af[1] + bf4.y;
            ff.z = af[2] + bf4.z;
            ff.w = af[3] + bf4.w;
            const size_t oidx = (size_t)n * 256 + kb;
            __builtin_nontemporal_store(hh, (f4v*)(out_h + oidx));
            __builtin_nontemporal_store(cc, (f4v*)(out_c + oidx));
            __builtin_nontemporal_store(ff, (f4v*)(out_f + oidx));
        }
    }
}

extern "C" void kernel_launch(void* const* d_in, const int* in_sizes, int n_in,
                              void* d_out, int out_size, void* d_ws, size_t ws_size,
                              hipStream_t stream) {
    const float* x     = (const float*)d_in[0];
    const float* Uh    = (const float*)d_in[1];
    const float* fc    = (const float*)d_in[2];
    const float* W_iou = (const float*)d_in[3];
    const float* b_iou = (const float*)d_in[4];
    const float* W_f   = (const float*)d_in[5];
    const float* b_f   = (const float*)d_in[6];
    float* out = (float*)d_out;
    short* wpk = (short*)d_ws;

    if (ws_size >= 512 * 1024) {
        pack_w<<<128, 256, 0, stream>>>(W_iou, W_f, wpk);
        treelstm_main<true><<<TILES, 512, 0, stream>>>(x, Uh, fc, W_iou, b_iou,
                                                       W_f, b_f, wpk, out);
    } else {
        treelstm_main<false><<<TILES, 512, 0, stream>>>(x, Uh, fc, W_iou, b_iou,
                                                        W_f, b_f, wpk, out);
    }
}